// Round 3
// baseline (330.507 us; speedup 1.0000x reference)
//
#include <hip/hip_runtime.h>
#include <math.h>

#define N_ROWS 8192
#define DIM    512
#define NT     (N_ROWS / 128)        // 64 block-tiles per dim
#define NBLK   (NT * (NT + 1) / 2)   // 2080 lower-triangle tiles (2080 % 8 == 0)

typedef __bf16 bf16x8 __attribute__((ext_vector_type(8)));
typedef float  floatx4 __attribute__((ext_vector_type(4)));

__device__ __forceinline__ unsigned short f2bf_rne(float x) {
    union { float f; unsigned u; } v; v.f = x;
    unsigned r = v.u + 0x7FFFu + ((v.u >> 16) & 1u);
    return (unsigned short)(r >> 16);
}

// async global->LDS, 16B per lane. LDS dest must be wave-uniform base + lane*16.
__device__ __forceinline__ void async_cp16(const void* g, void* l) {
    __builtin_amdgcn_global_load_lds(
        (const __attribute__((address_space(1))) unsigned int*)g,
        (__attribute__((address_space(3))) unsigned int*)l,
        16, 0, 0);
}

// Kernel 1: one wave per row. fp32 sq_norm + bf16 convert. (~8 us, unchanged)
__global__ __launch_bounds__(256) void fs_norm_convert(
    const float* __restrict__ F, unsigned short* __restrict__ Fb,
    float* __restrict__ sn) {
    const int wave = threadIdx.x >> 6;
    const int lane = threadIdx.x & 63;
    const int row  = blockIdx.x * 4 + wave;

    const float4* src = reinterpret_cast<const float4*>(F + (size_t)row * DIM) + lane * 2;
    float4 x0 = src[0];
    float4 x1 = src[1];

    float ss = x0.x*x0.x + x0.y*x0.y + x0.z*x0.z + x0.w*x0.w
             + x1.x*x1.x + x1.y*x1.y + x1.z*x1.z + x1.w*x1.w;

    uint4 p;
    p.x = (unsigned)f2bf_rne(x0.x) | ((unsigned)f2bf_rne(x0.y) << 16);
    p.y = (unsigned)f2bf_rne(x0.z) | ((unsigned)f2bf_rne(x0.w) << 16);
    p.z = (unsigned)f2bf_rne(x1.x) | ((unsigned)f2bf_rne(x1.y) << 16);
    p.w = (unsigned)f2bf_rne(x1.z) | ((unsigned)f2bf_rne(x1.w) << 16);
    reinterpret_cast<uint4*>(Fb + (size_t)row * DIM)[lane] = p;

    #pragma unroll
    for (int off = 32; off > 0; off >>= 1) ss += __shfl_down(ss, off);
    if (lane == 0) sn[row] = ss;
}

// Kernel 2: symmetric GEMM, lower-triangle block tiles only, single acc.
// Round-3 change: NO LDS transpose for the mirror tile. C-fragment layout
// (col=l16, row=quad*4+rr) means acc[i][j][0..3] are 4 CONSECUTIVE COLUMNS
// of one row in the mirror tile -> store mirror directly from registers as
// one dwordx4 per (i,j). Deletes 128 LDS ops + 48 store issues per lane.
// Output stores are nontemporal (never re-read) so the 268 MB write stream
// stops evicting the 8 MiB Fb panels from per-XCD L2.
// Kept (verified good): BK=64 XOR-swizzled staging (bank conflicts = 0),
// double-buffered global_load_lds prefetch, triangle grid + bijective XCD
// chunking, single accumulator (no spill).
__global__ __launch_bounds__(256, 2) void fs_gemm_sym(
    const unsigned short* __restrict__ Fb, const float* __restrict__ sn,
    float* __restrict__ out) {
    __shared__ unsigned short As[2][128 * 64];   // 16 KiB per buf
    __shared__ unsigned short Bs[2][128 * 64];   // 64 KiB total -> 2 blocks/CU

    const int tid  = threadIdx.x;
    const int lane = tid & 63;
    const int wave = tid >> 6;
    const int wr   = wave >> 1;      // wave row 0..1
    const int wc   = wave & 1;       // wave col 0..1
    const int quad = lane >> 4;      // 0..3
    const int l16  = lane & 15;

    // XCD-aware chunking (bijective: 2080 = 8*260), then linear->triangle.
    int L = (int)blockIdx.x;
    L = (L & 7) * (NBLK / 8) + (L >> 3);
    int bi = (int)((sqrtf(8.0f * (float)L + 1.0f) - 1.0f) * 0.5f);
    while ((bi + 1) * (bi + 2) / 2 <= L) ++bi;   // fixup fp sqrt
    while (bi * (bi + 1) / 2 > L) --bi;
    const int bj   = L - bi * (bi + 1) / 2;
    const int diag = (bi == bj);

    const int bRow = bi * 128;
    const int bCol = bj * 128;

    floatx4 acc[4][4];
    #pragma unroll
    for (int i = 0; i < 4; ++i)
        #pragma unroll
        for (int j = 0; j < 4; ++j)
            acc[i][j] = floatx4{0.f, 0.f, 0.f, 0.f};

    // Staging: thread tid covers rows r, r+32, r+64, r+96; col-group c (8 elems).
    // Source col-group is pre-swizzled: csw = c ^ (r&7); rows r+32k share r&7.
    const int r   = tid >> 3;        // 0..31
    const int c   = tid & 7;         // 0..7
    const int csw = c ^ (r & 7);
    const unsigned short* gA = Fb + (size_t)(bRow + r) * DIM + csw * 8;
    const unsigned short* gB = Fb + (size_t)(bCol + r) * DIM + csw * 8;

    // Fragment read col offsets (elements), swizzled; rows read have row&7 == l16&7.
    const int cg0 = ((0 + quad) ^ (l16 & 7)) * 8;   // k-half 0
    const int cg1 = ((4 + quad) ^ (l16 & 7)) * 8;   // k-half 1

    #define STAGE(buf, k0) {                                        \
        unsigned short* la = &As[buf][tid * 8];                     \
        unsigned short* lb = &Bs[buf][tid * 8];                     \
        const unsigned short* pa = gA + (k0);                       \
        const unsigned short* pb = gB + (k0);                       \
        async_cp16(pa,            la);                              \
        async_cp16(pa + 32 * DIM, la + 2048);                       \
        async_cp16(pa + 64 * DIM, la + 4096);                       \
        async_cp16(pa + 96 * DIM, la + 6144);                       \
        async_cp16(pb,            lb);                              \
        async_cp16(pb + 32 * DIM, lb + 2048);                       \
        async_cp16(pb + 64 * DIM, lb + 4096);                       \
        async_cp16(pb + 96 * DIM, lb + 6144);                       \
    }

    STAGE(0, 0)
    __syncthreads();   // drain prologue stage

    for (int k = 0; k < DIM / 64; ++k) {
        if (k < DIM / 64 - 1) STAGE((k + 1) & 1, (k + 1) * 64)   // prefetch next
        const unsigned short* Ab = As[k & 1];
        const unsigned short* Bb = Bs[k & 1];
        #pragma unroll
        for (int h = 0; h < 2; ++h) {
            const int cg = h ? cg1 : cg0;
            bf16x8 af[4], bf[4];
            #pragma unroll
            for (int t = 0; t < 4; ++t) {
                af[t] = *reinterpret_cast<const bf16x8*>(
                    Ab + (wr * 64 + t * 16 + l16) * 64 + cg);
                bf[t] = *reinterpret_cast<const bf16x8*>(
                    Bb + (wc * 64 + t * 16 + l16) * 64 + cg);
            }
            #pragma unroll
            for (int i = 0; i < 4; ++i)
                #pragma unroll
                for (int j = 0; j < 4; ++j)
                    acc[i][j] = __builtin_amdgcn_mfma_f32_16x16x32_bf16(
                        af[i], bf[j], acc[i][j], 0, 0, 0);
        }
        if (k < DIM / 64 - 1) __syncthreads();   // prefetched tile ready; reads done
        // (no barrier after last iter: epilogue is register-only)
    }

    // Epilogue. C/D layout: col = lane&15, row = quad*4 + reg.
    // Main tile (bi,bj): 4 scalar NT stores per (i,j), 64B-coalesced per quad.
    // Mirror tile (bj,bi): acc[i][j][0..3] = one row', 4 consecutive cols'
    // -> single NT dwordx4 per (i,j), 16B aligned (rbase multiple of 4).
    const int row0 = bRow + wr * 64;
    const int col0 = bCol + wc * 64;
    float snc[4];
    #pragma unroll
    for (int j = 0; j < 4; ++j) snc[j] = sn[col0 + j * 16 + l16];

    #pragma unroll
    for (int i = 0; i < 4; ++i) {
        const int rbase = row0 + i * 16 + quad * 4;
        const floatx4 snr4 = *reinterpret_cast<const floatx4*>(sn + rbase);
        #pragma unroll
        for (int j = 0; j < 4; ++j) {
            const int col = col0 + j * 16 + l16;
            floatx4 ov;
            #pragma unroll
            for (int rr = 0; rr < 4; ++rr) {
                float v = snr4[rr] + snc[j] - 2.0f * acc[i][j][rr];
                float o = -sqrtf(fmaxf(v, 0.0f));
                ov[rr] = (rbase + rr == col) ? 0.0f : o;
            }
            #pragma unroll
            for (int rr = 0; rr < 4; ++rr)
                __builtin_nontemporal_store(
                    ov[rr], out + (size_t)(rbase + rr) * N_ROWS + col);
            if (!diag)
                __builtin_nontemporal_store(
                    ov, reinterpret_cast<floatx4*>(
                            out + (size_t)col * N_ROWS + rbase));
        }
    }
}

extern "C" void kernel_launch(void* const* d_in, const int* in_sizes, int n_in,
                              void* d_out, int out_size, void* d_ws, size_t ws_size,
                              hipStream_t stream) {
    const float* F = (const float*)d_in[0];
    float* out = (float*)d_out;

    unsigned short* Fb = (unsigned short*)d_ws;                       // 8 MiB bf16 copy
    float* sn = (float*)((char*)d_ws + (size_t)N_ROWS * DIM * 2);     // 32 KiB norms

    fs_norm_convert<<<N_ROWS / 4, 256, 0, stream>>>(F, Fb, sn);

    fs_gemm_sym<<<dim3(NBLK), 256, 0, stream>>>(Fb, sn, out);
}

// Round 5
// 327.207 us; speedup vs baseline: 1.0101x; 1.0101x over previous
//
#include <hip/hip_runtime.h>
#include <math.h>

#define N_ROWS 8192
#define DIM    512
#define NT     (N_ROWS / 128)        // 64 block-tiles per dim
#define NBLK   (NT * (NT + 1) / 2)   // 2080 lower-triangle tiles (2080 % 8 == 0)

typedef __bf16 bf16x8 __attribute__((ext_vector_type(8)));
typedef float  floatx4 __attribute__((ext_vector_type(4)));

__device__ __forceinline__ unsigned short f2bf_rne(float x) {
    union { float f; unsigned u; } v; v.f = x;
    unsigned r = v.u + 0x7FFFu + ((v.u >> 16) & 1u);
    return (unsigned short)(r >> 16);
}

// async global->LDS, 16B per lane. LDS dest must be wave-uniform base + lane*16.
__device__ __forceinline__ void async_cp16(const void* g, void* l) {
    __builtin_amdgcn_global_load_lds(
        (const __attribute__((address_space(1))) unsigned int*)g,
        (__attribute__((address_space(3))) unsigned int*)l,
        16, 0, 0);
}

// Kernel 1: one wave per row. fp32 sq_norm + bf16 convert. (~8 us, unchanged)
__global__ __launch_bounds__(256) void fs_norm_convert(
    const float* __restrict__ F, unsigned short* __restrict__ Fb,
    float* __restrict__ sn) {
    const int wave = threadIdx.x >> 6;
    const int lane = threadIdx.x & 63;
    const int row  = blockIdx.x * 4 + wave;

    const float4* src = reinterpret_cast<const float4*>(F + (size_t)row * DIM) + lane * 2;
    float4 x0 = src[0];
    float4 x1 = src[1];

    float ss = x0.x*x0.x + x0.y*x0.y + x0.z*x0.z + x0.w*x0.w
             + x1.x*x1.x + x1.y*x1.y + x1.z*x1.z + x1.w*x1.w;

    uint4 p;
    p.x = (unsigned)f2bf_rne(x0.x) | ((unsigned)f2bf_rne(x0.y) << 16);
    p.y = (unsigned)f2bf_rne(x0.z) | ((unsigned)f2bf_rne(x0.w) << 16);
    p.z = (unsigned)f2bf_rne(x1.x) | ((unsigned)f2bf_rne(x1.y) << 16);
    p.w = (unsigned)f2bf_rne(x1.z) | ((unsigned)f2bf_rne(x1.w) << 16);
    reinterpret_cast<uint4*>(Fb + (size_t)row * DIM)[lane] = p;

    #pragma unroll
    for (int off = 32; off > 0; off >>= 1) ss += __shfl_down(ss, off);
    if (lane == 0) sn[row] = ss;
}

// Kernel 2: symmetric GEMM, lower-triangle tiles, single accumulator.
// Round-5 == round-4 resubmit (container infra failure, kernel never ran).
// All-vector coalesced epilogue. Evidence (r0 vs r2 vs r3): the
// store/epilogue side is ~116 of ~150 us -- issue/transaction-bound, not
// byte-bound. Fix: overwrite acc with finished -sqrt values, then use the
// per-wave 16 KiB LDS region (staging bufs, dead post-K-loop) as a 64x64
// f32 transpose buffer with swizzle chunk ^= (row&15) (all 4 access
// patterns at the bank floor, verified by enumeration):
//   pass 1 (main):   64 swz ds_write_b32 -> 16 ds_read_b128 -> 16 x4 stores
//   pass 2 (mirror): 16 ds_write_b128 (acc is 4 consecutive T^T cols)
//                    -> 16 ds_read_b128 -> 16 x4 stores
// Store instrs/lane 80->32, transactions/wave ~1280->~256, all 256B-
// contiguous per instr. NT removed (L2 write-back coalesces the stream).
// Kept: BK=64 XOR-swizzled staging (0 conflicts), double-buffered
// global_load_lds prefetch, triangle grid + bijective XCD chunking.
__global__ __launch_bounds__(256, 2) void fs_gemm_sym(
    const unsigned short* __restrict__ Fb, const float* __restrict__ sn,
    float* __restrict__ out) {
    // [0]=As buf0, [1]=As buf1, [2]=Bs buf0, [3]=Bs buf1  (64 KiB total).
    // Post-K-loop: 4 x 16 KiB per-wave f32 transpose scratch.
    __shared__ unsigned short smem[4][128 * 64];

    const int tid  = threadIdx.x;
    const int lane = tid & 63;
    const int wave = tid >> 6;
    const int wr   = wave >> 1;      // wave row 0..1
    const int wc   = wave & 1;       // wave col 0..1
    const int quad = lane >> 4;      // 0..3
    const int l16  = lane & 15;

    // XCD-aware chunking (bijective: 2080 = 8*260), then linear->triangle.
    int L = (int)blockIdx.x;
    L = (L & 7) * (NBLK / 8) + (L >> 3);
    int bi = (int)((sqrtf(8.0f * (float)L + 1.0f) - 1.0f) * 0.5f);
    while ((bi + 1) * (bi + 2) / 2 <= L) ++bi;   // fixup fp sqrt
    while (bi * (bi + 1) / 2 > L) --bi;
    const int bj   = L - bi * (bi + 1) / 2;
    const int diag = (bi == bj);

    const int bRow = bi * 128;
    const int bCol = bj * 128;

    floatx4 acc[4][4];
    #pragma unroll
    for (int i = 0; i < 4; ++i)
        #pragma unroll
        for (int j = 0; j < 4; ++j)
            acc[i][j] = floatx4{0.f, 0.f, 0.f, 0.f};

    // Staging: thread tid covers rows r, r+32, r+64, r+96; col-group c (8 elems).
    // Source col-group is pre-swizzled: csw = c ^ (r&7); rows r+32k share r&7.
    const int r   = tid >> 3;        // 0..31
    const int c   = tid & 7;         // 0..7
    const int csw = c ^ (r & 7);
    const unsigned short* gA = Fb + (size_t)(bRow + r) * DIM + csw * 8;
    const unsigned short* gB = Fb + (size_t)(bCol + r) * DIM + csw * 8;

    // Fragment read col offsets (elements), swizzled; rows read have row&7 == l16&7.
    const int cg0 = ((0 + quad) ^ (l16 & 7)) * 8;   // k-half 0
    const int cg1 = ((4 + quad) ^ (l16 & 7)) * 8;   // k-half 1

    #define STAGE(buf, k0) {                                        \
        unsigned short* la = &smem[buf][tid * 8];                   \
        unsigned short* lb = &smem[2 + (buf)][tid * 8];             \
        const unsigned short* pa = gA + (k0);                       \
        const unsigned short* pb = gB + (k0);                       \
        async_cp16(pa,            la);                              \
        async_cp16(pa + 32 * DIM, la + 2048);                       \
        async_cp16(pa + 64 * DIM, la + 4096);                       \
        async_cp16(pa + 96 * DIM, la + 6144);                       \
        async_cp16(pb,            lb);                              \
        async_cp16(pb + 32 * DIM, lb + 2048);                       \
        async_cp16(pb + 64 * DIM, lb + 4096);                       \
        async_cp16(pb + 96 * DIM, lb + 6144);                       \
    }

    STAGE(0, 0)
    __syncthreads();   // drain prologue stage

    for (int k = 0; k < DIM / 64; ++k) {
        if (k < DIM / 64 - 1) STAGE((k + 1) & 1, (k + 1) * 64)   // prefetch next
        const unsigned short* Ab = smem[k & 1];
        const unsigned short* Bb = smem[2 + (k & 1)];
        #pragma unroll
        for (int h = 0; h < 2; ++h) {
            const int cg = h ? cg1 : cg0;
            bf16x8 af[4], bf[4];
            #pragma unroll
            for (int t = 0; t < 4; ++t) {
                af[t] = *reinterpret_cast<const bf16x8*>(
                    Ab + (wr * 64 + t * 16 + l16) * 64 + cg);
                bf[t] = *reinterpret_cast<const bf16x8*>(
                    Bb + (wc * 64 + t * 16 + l16) * 64 + cg);
            }
            #pragma unroll
            for (int i = 0; i < 4; ++i)
                #pragma unroll
                for (int j = 0; j < 4; ++j)
                    acc[i][j] = __builtin_amdgcn_mfma_f32_16x16x32_bf16(
                        af[i], bf[j], acc[i][j], 0, 0, 0);
        }
        __syncthreads();   // also serves as the pre-epilogue sync on k==7
    }

    // ---- Epilogue ----
    // Overwrite acc with output values. C/D layout: col=l16, row=quad*4+rr.
    const int row0 = bRow + wr * 64;
    const int col0 = bCol + wc * 64;
    {
        float snc[4];
        #pragma unroll
        for (int j = 0; j < 4; ++j) snc[j] = sn[col0 + j * 16 + l16];
        #pragma unroll
        for (int i = 0; i < 4; ++i) {
            const int rbase = row0 + i * 16 + quad * 4;
            const floatx4 snr4 = *reinterpret_cast<const floatx4*>(sn + rbase);
            #pragma unroll
            for (int j = 0; j < 4; ++j) {
                const int col = col0 + j * 16 + l16;
                #pragma unroll
                for (int rr = 0; rr < 4; ++rr) {
                    float v = snr4[rr] + snc[j] - 2.0f * acc[i][j][rr];
                    float o = -sqrtf(fmaxf(v, 0.0f));
                    acc[i][j][rr] = (rbase + rr == col) ? 0.0f : o;
                }
            }
        }
    }

    // Per-wave 64x64 f32 tile T in LDS, swizzled: element (r,c) lives at
    // r*64 + ((c>>2) ^ (r&15))*4 + (c&3).  (16B chunk index XOR'd with r&15.)
    float* tbuf = reinterpret_cast<float*>(&smem[0][0]) + wave * 4096;

    // Pass 1 — main tile (bi,bj). Scatter scalars (2 lanes/bank = free),
    // gather rows as b128, store 256B-contiguous x4 per instr.
    #pragma unroll
    for (int i = 0; i < 4; ++i) {
        const int rloc = i * 16 + quad * 4;
        #pragma unroll
        for (int j = 0; j < 4; ++j) {
            const int cloc = j * 16 + l16;
            #pragma unroll
            for (int rr = 0; rr < 4; ++rr) {
                const int rw = rloc + rr;
                tbuf[rw * 64 + ((((cloc >> 2) ^ (rw & 15)) << 2) | (cloc & 3))] =
                    acc[i][j][rr];
            }
        }
    }
    #pragma unroll
    for (int s = 0; s < 16; ++s) {
        const int rT = s * 4 + quad;
        const floatx4 q4 = *reinterpret_cast<const floatx4*>(
            tbuf + rT * 64 + ((l16 ^ (rT & 15)) << 2));
        *reinterpret_cast<floatx4*>(
            out + (size_t)(row0 + rT) * N_ROWS + col0 + l16 * 4) = q4;
    }

    // Pass 2 — mirror tile (bj,bi). acc[i][j][0..3] = 4 consecutive columns
    // of one T^T row -> direct b128 writes, then coalesced row reads.
    if (!diag) {
        #pragma unroll
        for (int i = 0; i < 4; ++i) {
            const int rloc4 = 4 * i + quad;           // (i*16+quad*4)>>2
            #pragma unroll
            for (int j = 0; j < 4; ++j) {
                const int cloc = j * 16 + l16;        // T^T row index
                *reinterpret_cast<floatx4*>(
                    tbuf + cloc * 64 + ((rloc4 ^ (cloc & 15)) << 2)) = acc[i][j];
            }
        }
        #pragma unroll
        for (int s = 0; s < 16; ++s) {
            const int rT = s * 4 + quad;              // T^T row = mirror row - col0
            const floatx4 q4 = *reinterpret_cast<const floatx4*>(
                tbuf + rT * 64 + ((l16 ^ (rT & 15)) << 2));
            *reinterpret_cast<floatx4*>(
                out + (size_t)(col0 + rT) * N_ROWS + row0 + l16 * 4) = q4;
        }
    }
}

extern "C" void kernel_launch(void* const* d_in, const int* in_sizes, int n_in,
                              void* d_out, int out_size, void* d_ws, size_t ws_size,
                              hipStream_t stream) {
    const float* F = (const float*)d_in[0];
    float* out = (float*)d_out;

    unsigned short* Fb = (unsigned short*)d_ws;                       // 8 MiB bf16 copy
    float* sn = (float*)((char*)d_ws + (size_t)N_ROWS * DIM * 2);     // 32 KiB norms

    fs_norm_convert<<<N_ROWS / 4, 256, 0, stream>>>(F, Fb, sn);

    fs_gemm_sym<<<dim3(NBLK), 256, 0, stream>>>(Fb, sn, out);
}